// Round 1
// baseline (31724.930 us; speedup 1.0000x reference)
//
#include <hip/hip_runtime.h>
#include <math.h>

// Decoder_82231443849250: persistent-kernel recurrent MLP decoder.
// 8 batch-groups (32 rows each) x 32 WGs (32-col N-slices). 5 group barriers
// per step via monotonic device-scope atomic counters. bf16 MFMA 16x16x32 for
// the H x H GEMMs; f32 for LN stats / accumulators / state.

#define NB 256
#define NS 128
#define NH 1024
#define NJ 12
#define NPIN 139
#define NPD 42
#define NGRP 8
#define WPG 32
#define BROW 32
#define W2S 1032  // LDS row stride in ushorts (pad 8 -> conflict-light, 16B aligned)

typedef __attribute__((ext_vector_type(8))) short short8;
typedef __attribute__((ext_vector_type(4))) float f32x4;
typedef __attribute__((ext_vector_type(4))) unsigned short u16x4;

struct Params {
  const float* z; const float* obs; const float* W1; const float* b1;
  const float* g1; const float* be1; const float* W2; const float* b2;
  const float* g2; const float* be2; const float* Wa1; const float* ba1;
  const float* Wa2; const float* ba2; const float* Wo; const float* bo;
  const float* Wv; const float* bv; const float* alog; const float* fkW;
  const float* fkb; const float* pmean; const float* pstd; const float* jlo;
  const float* jhi; const float* ddp;
  float* out_gmu; float* out_joint; float* out_act; float* out_ls;
  float* zc; float* y1; float* y2;
  unsigned short* h1; unsigned short* hh; unsigned short* t1;
  unsigned short* wa1b; unsigned short* wa2b; unsigned short* wexb;
  unsigned int* gcnt; unsigned int* cnt;
};

__device__ __forceinline__ unsigned short f2bf(float x) {
  union { float f; unsigned u; } v; v.f = x;
  unsigned r = v.u + 0x7FFFu + ((v.u >> 16) & 1u);
  return (unsigned short)(r >> 16);
}

// [32 rows or cols,16] x K=1024 bf16 MFMA dot; both operands row-major over k.
// A/B k-slot layout cancels as long as A and B are loaded identically
// (HW pairs A-slot with B-slot of the same k). D: col=lane&15, row=(lane>>4)*4+i.
__device__ __forceinline__ f32x4 dot1024(const unsigned short* a, const unsigned short* b) {
  const short8* ap = (const short8*)a;
  const short8* bp = (const short8*)b;
  f32x4 acc0 = {0.f, 0.f, 0.f, 0.f};
  f32x4 acc1 = {0.f, 0.f, 0.f, 0.f};
#pragma unroll 4
  for (int k8 = 0; k8 < 128; k8 += 8) {
    acc0 = __builtin_amdgcn_mfma_f32_16x16x32_bf16(ap[k8], bp[k8], acc0, 0, 0, 0);
    acc1 = __builtin_amdgcn_mfma_f32_16x16x32_bf16(ap[k8 + 4], bp[k8 + 4], acc1, 0, 0, 0);
  }
  return acc0 + acc1;
}

// Monotonic-counter barrier: no reset, no generations. target = (#calls)*arrivals.
__device__ __forceinline__ void gbar(unsigned int* c, unsigned int target) {
  __threadfence();              // release: my stores visible agent-wide
  __syncthreads();              // all threads of WG fenced before arrival
  if (threadIdx.x == 0) {
    __hip_atomic_fetch_add(c, 1u, __ATOMIC_RELEASE, __HIP_MEMORY_SCOPE_AGENT);
    while (__hip_atomic_load(c, __ATOMIC_ACQUIRE, __HIP_MEMORY_SCOPE_AGENT) < target)
      __builtin_amdgcn_s_sleep(2);
  }
  __syncthreads();
  __threadfence();              // acquire side: invalidate L1 for all waves
}

__global__ __launch_bounds__(256, 2) void decoder_persistent(Params p) {
  __shared__ unsigned short w2l[BROW * W2S];          // 66048 B: W2 col-slice, bf16
  __shared__ float pj_l[BROW * NJ];                   // carried joints (replicated/WG)
  __shared__ float pdq_l[BROW * NJ];                  // carried dq
  __shared__ float aex[BROW * 16];                    // a exchange (post-tanh)
  __shared__ float redm[4], redq[4];                  // LN reduce scratch
  __shared__ float alpha_l[NJ], jm_l[NJ], jri_l[NJ], lo_l[NJ], hi_l[NJ], ddp_l[NJ], ba2_l[NJ];
  __shared__ float pm_l[NPD], psi_l[NPD], bv_l[NPD], bo_l[4];

  const int tid = threadIdx.x;
  const int bid = blockIdx.x;
  const int g = bid & 7;        // group -> same XCD under %8 round-robin heuristic
  const int w = bid >> 3;       // WG-in-group: owns cols [w*32, w*32+32)
  const int b0 = g * BROW;
  const int n0 = w * 32;
  const int wave = tid >> 6;
  const int lane = tid & 63;

  unsigned int* cg = p.cnt + g * 64;  // own 256B line per group

  float* y1g = p.y1 + (size_t)g * BROW * NH;
  float* y2g = p.y2 + (size_t)g * BROW * NH;
  unsigned short* h1g = p.h1 + (size_t)g * BROW * NH;
  unsigned short* hg = p.hh + (size_t)g * BROW * NH;
  unsigned short* t1g = p.t1 + (size_t)g * BROW * NH;

  // ---------------- P0: one-time setup ----------------
  if (tid < NJ) {
    alpha_l[tid] = 1.f / (1.f + expf(-p.alog[tid]));
    float lo = p.jlo[tid], hi = p.jhi[tid];
    jm_l[tid] = 0.5f * (hi + lo);
    jri_l[tid] = 2.f / (hi - lo);
    lo_l[tid] = lo; hi_l[tid] = hi;
    ddp_l[tid] = p.ddp[tid]; ba2_l[tid] = p.ba2[tid];
  }
  if (tid < NPD) { pm_l[tid] = p.pmean[tid]; psi_l[tid] = 1.f / p.pstd[tid]; bv_l[tid] = p.bv[tid]; }
  if (tid < 3) bo_l[tid] = p.bo[tid];
  for (int idx = tid; idx < BROW * NJ; idx += 256) { pj_l[idx] = p.ddp[idx % NJ]; pdq_l[idx] = 0.f; }
  // W2 slice -> LDS bf16
  for (int idx = tid; idx < BROW * NH; idx += 256) {
    int r = idx >> 10, k = idx & (NH - 1);
    w2l[r * W2S + k] = f2bf(p.W2[(size_t)(n0 + r) * NH + k]);
  }
  // zc = z @ W1z^T + b1  (constant across steps)
  {
    int r = tid >> 3, cq = tid & 7;
    int nb = n0 + cq * 4;
    const float* zr = p.z + (size_t)(b0 + r) * 64;
    const float* w1r = p.W1 + (size_t)nb * NPIN + 75;
    float a0 = p.b1[nb], a1 = p.b1[nb + 1], a2 = p.b1[nb + 2], a3 = p.b1[nb + 3];
    for (int k = 0; k < 64; ++k) {
      float zv = zr[k];
      a0 += zv * w1r[k]; a1 += zv * w1r[NPIN + k];
      a2 += zv * w1r[2 * NPIN + k]; a3 += zv * w1r[3 * NPIN + k];
    }
    f32x4 st = {a0, a1, a2, a3};
    *(f32x4*)(p.zc + (size_t)(b0 + r) * NH + nb) = st;
  }
  // Wa1 -> bf16 ws (rows n0+g*4 .. +3 : all (g,w) cover 1024 rows exactly once)
  for (int idx = tid; idx < 4 * NH; idx += 256) {
    int r = idx >> 10, k = idx & (NH - 1);
    int row = n0 + g * 4 + r;
    p.wa1b[(size_t)row * NH + k] = f2bf(p.Wa1[(size_t)row * NH + k]);
  }
  if (bid == 0) {  // Wa2 padded to 16 rows
    for (int idx = tid; idx < 16 * NH; idx += 256) {
      int r = idx >> 10, k = idx & (NH - 1);
      p.wa2b[idx] = (r < NJ) ? f2bf(p.Wa2[(size_t)r * NH + k]) : (unsigned short)0;
    }
  }
  if (bid == 1) {  // [Wo(3); Wv(42); zeros(3)] padded to 48 rows
    for (int idx = tid; idx < 48 * NH; idx += 256) {
      int r = idx >> 10, k = idx & (NH - 1);
      unsigned short v = 0;
      if (r < 3) v = f2bf(p.Wo[(size_t)r * NH + k]);
      else if (r < 45) v = f2bf(p.Wv[(size_t)(r - 3) * NH + k]);
      p.wexb[idx] = v;
    }
  }
  gbar(p.gcnt, 256u);  // global one-time barrier (ws conversions cross groups)

  // ---------------- phase lambdas ----------------
  auto ln_row = [&](const float* y, const float* gamma, const float* beta,
                    unsigned short* hout) {
    f32x4 v = *(const f32x4*)(y + tid * 4);
    float s = v[0] + v[1] + v[2] + v[3];
    float q = v[0] * v[0] + v[1] * v[1] + v[2] * v[2] + v[3] * v[3];
#pragma unroll
    for (int off = 32; off; off >>= 1) {
      s += __shfl_down(s, off, 64);
      q += __shfl_down(q, off, 64);
    }
    if (lane == 0) { redm[wave] = s; redq[wave] = q; }
    __syncthreads();
    float m = (redm[0] + redm[1] + redm[2] + redm[3]) * (1.0f / 1024.0f);
    float e2 = (redq[0] + redq[1] + redq[2] + redq[3]) * (1.0f / 1024.0f);
    float rs = rsqrtf(e2 - m * m + 1e-5f);
    u16x4 hv;
#pragma unroll
    for (int i = 0; i < 4; ++i) {
      int c = tid * 4 + i;
      float x = (v[i] - m) * rs * gamma[c] + beta[c];
      hv[i] = f2bf(fmaxf(x, 0.f));
    }
    *(u16x4*)(hout + tid * 4) = hv;
  };

  auto P1 = [&](int t) {  // y1 slice = zc + [jn|pdq]@W1a + obs_t@W1o  (f32)
    int r = tid >> 3, cq = tid & 7;
    int nb = n0 + cq * 4;
    float xj[24];
#pragma unroll
    for (int j = 0; j < NJ; ++j) {
      xj[j] = (pj_l[r * NJ + j] - jm_l[j]) * jri_l[j];
      xj[12 + j] = pdq_l[r * NJ + j];
    }
    f32x4 acc = *(const f32x4*)(p.zc + (size_t)(b0 + r) * NH + nb);
    const float* w1r = p.W1 + (size_t)nb * NPIN;
#pragma unroll
    for (int k = 0; k < 24; ++k) {
      float xv = xj[k];
      acc[0] += xv * w1r[k]; acc[1] += xv * w1r[NPIN + k];
      acc[2] += xv * w1r[2 * NPIN + k]; acc[3] += xv * w1r[3 * NPIN + k];
    }
    const float* ob = p.obs + ((size_t)(b0 + r) * NS + t) * 51;
    for (int o = 0; o < 51; ++o) {
      float ov = ob[o];
      acc[0] += ov * w1r[24 + o]; acc[1] += ov * w1r[NPIN + 24 + o];
      acc[2] += ov * w1r[2 * NPIN + 24 + o]; acc[3] += ov * w1r[3 * NPIN + 24 + o];
    }
    *(f32x4*)(y1g + (size_t)r * NH + nb) = acc;
  };

  auto P2 = [&]() {  // y2 slice = h1 @ W2slice^T + b2 (W2 from LDS)
    int rt = wave >> 1, ct = wave & 1;
    int kq = (lane >> 4) * 8;
    const unsigned short* a = h1g + (size_t)(rt * 16 + (lane & 15)) * NH + kq;
    const unsigned short* b = &w2l[(ct * 16 + (lane & 15)) * W2S + kq];
    f32x4 acc = dot1024(a, b);
    int col = n0 + ct * 16 + (lane & 15);
    float b2v = p.b2[col];
#pragma unroll
    for (int i = 0; i < 4; ++i) {
      int row = rt * 16 + (lane >> 4) * 4 + i;
      y2g[(size_t)row * NH + col] = acc[i] + b2v;
    }
  };

  auto P3 = [&](int t) {  // t1 slice = relu(h @ Wa1slice^T + ba1); extras: obj/sigma
    int rt = wave >> 1, ct = wave & 1;
    int kq = (lane >> 4) * 8;
    {
      const unsigned short* a = hg + (size_t)(rt * 16 + (lane & 15)) * NH + kq;
      const unsigned short* b = p.wa1b + (size_t)(n0 + ct * 16 + (lane & 15)) * NH + kq;
      f32x4 acc = dot1024(a, b);
      int col = n0 + ct * 16 + (lane & 15);
      float bav = p.ba1[col];
#pragma unroll
      for (int i = 0; i < 4; ++i) {
        int row = rt * 16 + (lane >> 4) * 4 + i;
        t1g[(size_t)row * NH + col] = f2bf(fmaxf(acc[i] + bav, 0.f));
      }
    }
    if (w >= 26 && wave == 3) {  // 6 extra 16x16 tiles: [Wo|Wv] heads
      int e = w - 26, cte = e >> 1, rte = e & 1;
      const unsigned short* a = hg + (size_t)(rte * 16 + (lane & 15)) * NH + kq;
      const unsigned short* b = p.wexb + (size_t)(cte * 16 + (lane & 15)) * NH + kq;
      f32x4 acc = dot1024(a, b);
      int ec = cte * 16 + (lane & 15);
#pragma unroll
      for (int i = 0; i < 4; ++i) {
        int row = rte * 16 + (lane >> 4) * 4 + i;
        int bb = b0 + row;
        if (ec < 3) {
          float val = acc[i] + bo_l[ec];
          p.out_gmu[((size_t)bb * NS + t) * NPD + 39 + ec] = (val - pm_l[39 + ec]) * psi_l[39 + ec];
        } else if (ec < 45) {
          int sv = ec - 3;
          float val = acc[i] + bv_l[sv];
          float sig = 0.05f + 0.45f / (1.f + expf(-val));
          p.out_ls[((size_t)bb * NS + t) * NPD + sv] = logf(sig);
        }
      }
    }
  };

  auto P4 = [&](int tp) {  // a = tanh(t1 @ Wa2^T + ba2); state update; outputs
    if (wave < 2) {
      int rt = wave;
      int kq = (lane >> 4) * 8;
      const unsigned short* a = t1g + (size_t)(rt * 16 + (lane & 15)) * NH + kq;
      const unsigned short* b = p.wa2b + (size_t)(lane & 15) * NH + kq;
      f32x4 acc = dot1024(a, b);
      int j = lane & 15;
      if (j < NJ) {
#pragma unroll
        for (int i = 0; i < 4; ++i) {
          int row = rt * 16 + (lane >> 4) * 4 + i;
          aex[row * 16 + j] = tanhf(acc[i] + ba2_l[j]);
        }
      }
    }
    __syncthreads();
    for (int idx = tid; idx < BROW * NJ; idx += 256) {
      int r = idx / NJ, j = idx - r * NJ;
      float av = aex[r * 16 + j];
      float pj = pj_l[idx];
      float tgt = av * 0.25f + ddp_l[j];
      float cj = pj + alpha_l[j] * (tgt - pj);
      cj = fminf(fmaxf(cj, lo_l[j]), hi_l[j]);
      pdq_l[idx] = (cj - pj) * 30.f;
      pj_l[idx] = cj;
      if (w == 0) {
        size_t o = ((size_t)(b0 + r) * NS + tp) * NJ + j;
        p.out_joint[o] = cj;
        p.out_act[o] = av;
      }
    }
    __syncthreads();
    if (w == 0) {  // agent FK + normalize -> graph_x_mu[:, :, 0:39]
      for (int idx = tid; idx < BROW * 39; idx += 256) {
        int r = idx / 39, m = idx - r * 39;
        float s = p.fkb[m];
        const float* fw = p.fkW + m * NJ;
#pragma unroll
        for (int j = 0; j < NJ; ++j) s += pj_l[r * NJ + j] * fw[j];
        p.out_gmu[((size_t)(b0 + r) * NS + tp) * NPD + m] = (s - pm_l[m]) * psi_l[m];
      }
    }
    __syncthreads();
  };

  // ---------------- step loop: 5 group barriers / step ----------------
  unsigned int nbar = 0;
  for (int t = 0; t < NS; ++t) {
    if (t > 0) P4(t - 1);           // finish prev step (state), no barrier needed after
    P1(t);
    gbar(cg, (++nbar) * WPG);       // y1 complete
    ln_row(y1g + (size_t)w * NH, p.g1, p.be1, h1g + (size_t)w * NH);
    gbar(cg, (++nbar) * WPG);       // h1 complete
    P2();
    gbar(cg, (++nbar) * WPG);       // y2 complete
    ln_row(y2g + (size_t)w * NH, p.g2, p.be2, hg + (size_t)w * NH);
    gbar(cg, (++nbar) * WPG);       // h complete
    P3(t);
    gbar(cg, (++nbar) * WPG);       // t1 + heads complete
  }
  P4(NS - 1);
}

extern "C" void kernel_launch(void* const* d_in, const int* in_sizes, int n_in,
                              void* d_out, int out_size, void* d_ws, size_t ws_size,
                              hipStream_t stream) {
  (void)in_sizes; (void)n_in; (void)out_size; (void)ws_size;
  char* ws = (char*)d_ws;
  Params p;
  p.z = (const float*)d_in[0];   p.obs = (const float*)d_in[1];
  p.W1 = (const float*)d_in[2];  p.b1 = (const float*)d_in[3];
  p.g1 = (const float*)d_in[4];  p.be1 = (const float*)d_in[5];
  p.W2 = (const float*)d_in[6];  p.b2 = (const float*)d_in[7];
  p.g2 = (const float*)d_in[8];  p.be2 = (const float*)d_in[9];
  p.Wa1 = (const float*)d_in[10]; p.ba1 = (const float*)d_in[11];
  p.Wa2 = (const float*)d_in[12]; p.ba2 = (const float*)d_in[13];
  p.Wo = (const float*)d_in[14]; p.bo = (const float*)d_in[15];
  p.Wv = (const float*)d_in[16]; p.bv = (const float*)d_in[17];
  p.alog = (const float*)d_in[18];
  p.fkW = (const float*)d_in[19]; p.fkb = (const float*)d_in[20];
  p.pmean = (const float*)d_in[21]; p.pstd = (const float*)d_in[22];
  p.jlo = (const float*)d_in[23]; p.jhi = (const float*)d_in[24];
  p.ddp = (const float*)d_in[25];

  float* out = (float*)d_out;
  p.out_gmu = out;                                 // [256,128,42]
  p.out_joint = out + (size_t)256 * 128 * 42;      // [256,128,12]
  p.out_act = p.out_joint + (size_t)256 * 128 * 12;
  p.out_ls = p.out_act + (size_t)256 * 128 * 12;   // [256,128,42]

  p.gcnt = (unsigned int*)(ws + 0);
  p.cnt = (unsigned int*)(ws + 256);
  p.zc = (float*)(ws + 4096);
  p.y1 = (float*)(ws + 4096 + (1 << 20));
  p.y2 = (float*)(ws + 4096 + 2 * (1 << 20));
  p.h1 = (unsigned short*)(ws + 4096 + 3 * (1 << 20));
  p.hh = (unsigned short*)(ws + 4096 + 3 * (1 << 20) + (1 << 19));
  p.t1 = (unsigned short*)(ws + 4096 + 3 * (1 << 20) + 2 * (1 << 19));
  p.wa1b = (unsigned short*)(ws + 4096 + 3 * (1 << 20) + 3 * (1 << 19));
  p.wa2b = (unsigned short*)(ws + 4096 + 5 * (1 << 20) + 3 * (1 << 19));
  p.wexb = (unsigned short*)(ws + 4096 + 5 * (1 << 20) + 3 * (1 << 19) + 32768);

  // barrier counters must start at 0 each call (monotonic within a call)
  hipMemsetAsync(d_ws, 0, 4096, stream);
  decoder_persistent<<<dim3(256), dim3(256), 0, stream>>>(p);
}

// Round 4
// 9487.792 us; speedup vs baseline: 3.3438x; 3.3438x over previous
//
#include <hip/hip_runtime.h>
#include <math.h>

// Decoder_82231443849250: persistent-kernel recurrent MLP decoder.
// 8 batch-groups (32 rows each) x 32 WGs (32-col N-slices); group g = bid&7
// so a group's WGs land on one XCD under the default %8 round-robin mapping.
// Intra-group barrier: vmcnt(0) drain (L1 write-through => stores visible in
// XCD L2) + agent-scope relaxed atomic counter (atomics bypass L1, always
// fresh) + buffer_inv sc1 (L1-only invalidate, no writeback traffic).
// All spins carry an s_memrealtime bailout so bugs terminate instead of hang.

#define NB 256
#define NS 128
#define NH 1024
#define NJ 12
#define NPIN 139
#define NPD 42
#define WPG 32
#define BROW 32
#define W2S 1032  // LDS row stride in ushorts

typedef __attribute__((ext_vector_type(8))) short short8;
typedef __attribute__((ext_vector_type(4))) float f32x4;
typedef __attribute__((ext_vector_type(4))) unsigned short u16x4;

struct Params {
  const float* z; const float* obs; const float* W1; const float* b1;
  const float* g1; const float* be1; const float* W2; const float* b2;
  const float* g2; const float* be2; const float* Wa1; const float* ba1;
  const float* Wa2; const float* ba2; const float* Wo; const float* bo;
  const float* Wv; const float* bv; const float* alog; const float* fkW;
  const float* fkb; const float* pmean; const float* pstd; const float* jlo;
  const float* jhi; const float* ddp;
  float* out_gmu; float* out_joint; float* out_act; float* out_ls;
  float* zc; float* y1; float* y2;
  unsigned short* h1; unsigned short* hh; unsigned short* t1;
  unsigned short* wa1b; unsigned short* wa2b; unsigned short* wexb;
  unsigned int* gcnt; unsigned int* cnt;
};

__device__ __forceinline__ unsigned short f2bf(float x) {
  union { float f; unsigned u; } v; v.f = x;
  unsigned r = v.u + 0x7FFFu + ((v.u >> 16) & 1u);
  return (unsigned short)(r >> 16);
}

__device__ __forceinline__ f32x4 dot1024(const unsigned short* a, const unsigned short* b) {
  const short8* ap = (const short8*)a;
  const short8* bp = (const short8*)b;
  f32x4 acc0 = {0.f, 0.f, 0.f, 0.f};
  f32x4 acc1 = {0.f, 0.f, 0.f, 0.f};
#pragma unroll 4
  for (int k8 = 0; k8 < 128; k8 += 8) {
    acc0 = __builtin_amdgcn_mfma_f32_16x16x32_bf16(ap[k8], bp[k8], acc0, 0, 0, 0);
    acc1 = __builtin_amdgcn_mfma_f32_16x16x32_bf16(ap[k8 + 4], bp[k8 + 4], acc1, 0, 0, 0);
  }
  return acc0 + acc1;
}

// ---- one-time global barrier (cross-XCD safe): full fences, used once.
__device__ __forceinline__ void gbar(unsigned int* c, unsigned int target) {
  __threadfence();
  __syncthreads();
  if (threadIdx.x == 0) {
    __hip_atomic_fetch_add(c, 1u, __ATOMIC_RELEASE, __HIP_MEMORY_SCOPE_AGENT);
    unsigned long long t0 = __builtin_amdgcn_s_memrealtime();
    while (__hip_atomic_load(c, __ATOMIC_ACQUIRE, __HIP_MEMORY_SCOPE_AGENT) < target) {
      __builtin_amdgcn_s_sleep(16);
      if (__builtin_amdgcn_s_memrealtime() - t0 > (1ull << 25)) break;  // bail, never hang
    }
  }
  __syncthreads();
  __threadfence();
}

// ---- XCD-local barrier. Counter ops are uniform agent-scope relaxed atomic
// RMWs (execute at the coherence point, bypass L1 -> poll is always fresh,
// relaxed -> no wbl2/inv emitted by the compiler). Data: vmcnt(0) publishes
// (write-through L1), buffer_inv sc1 invalidates this CU's L1 before reads.
__device__ __forceinline__ void xbar(unsigned int* c, unsigned int target) {
  asm volatile("s_waitcnt vmcnt(0)" ::: "memory");
  __syncthreads();
  if (threadIdx.x == 0) {
    unsigned old = __hip_atomic_fetch_add(c, 1u, __ATOMIC_RELAXED, __HIP_MEMORY_SCOPE_AGENT);
    if (old + 1u < target) {
      unsigned long long t0 = __builtin_amdgcn_s_memrealtime();
      while (__hip_atomic_fetch_add(c, 0u, __ATOMIC_RELAXED, __HIP_MEMORY_SCOPE_AGENT) < target) {
        __builtin_amdgcn_s_sleep(2);
        if (__builtin_amdgcn_s_memrealtime() - t0 > (1ull << 23)) break;  // bail, never hang
      }
    }
  }
  __syncthreads();
  asm volatile("buffer_inv sc1" ::: "memory");  // invalidate vector L1 only
}

__global__ __launch_bounds__(256, 2) void decoder_persistent(Params p) {
  __shared__ unsigned short w2l[BROW * W2S];
  __shared__ float pj_l[BROW * NJ];
  __shared__ float pdq_l[BROW * NJ];
  __shared__ float aex[BROW * 16];
  __shared__ float redm[4], redq[4];
  __shared__ float alpha_l[NJ], jm_l[NJ], jri_l[NJ], lo_l[NJ], hi_l[NJ], ddp_l[NJ], ba2_l[NJ];
  __shared__ float pm_l[NPD], psi_l[NPD], bv_l[NPD], bo_l[4];

  const int tid = threadIdx.x;
  const int bid = blockIdx.x;
  const int g = bid & 7;        // group == XCD under default %8 round-robin
  const int w = bid >> 3;       // WG-in-group: owns cols [w*32, w*32+32)
  const int b0 = g * BROW;
  const int n0 = w * 32;
  const int wave = tid >> 6;
  const int lane = tid & 63;

  unsigned int* cg = p.cnt + g * 64;  // own 256B line per group

  float* y1g = p.y1 + (size_t)g * BROW * NH;
  float* y2g = p.y2 + (size_t)g * BROW * NH;
  unsigned short* h1g = p.h1 + (size_t)g * BROW * NH;
  unsigned short* hg = p.hh + (size_t)g * BROW * NH;
  unsigned short* t1g = p.t1 + (size_t)g * BROW * NH;

  // ---------------- P0: one-time setup ----------------
  if (tid < NJ) {
    alpha_l[tid] = 1.f / (1.f + expf(-p.alog[tid]));
    float lo = p.jlo[tid], hi = p.jhi[tid];
    jm_l[tid] = 0.5f * (hi + lo);
    jri_l[tid] = 2.f / (hi - lo);
    lo_l[tid] = lo; hi_l[tid] = hi;
    ddp_l[tid] = p.ddp[tid]; ba2_l[tid] = p.ba2[tid];
  }
  if (tid < NPD) { pm_l[tid] = p.pmean[tid]; psi_l[tid] = 1.f / p.pstd[tid]; bv_l[tid] = p.bv[tid]; }
  if (tid < 3) bo_l[tid] = p.bo[tid];
  for (int idx = tid; idx < BROW * NJ; idx += 256) { pj_l[idx] = p.ddp[idx % NJ]; pdq_l[idx] = 0.f; }
  for (int idx = tid; idx < BROW * NH; idx += 256) {
    int r = idx >> 10, k = idx & (NH - 1);
    w2l[r * W2S + k] = f2bf(p.W2[(size_t)(n0 + r) * NH + k]);
  }
  {  // zc = z @ W1z^T + b1 (constant across steps)
    int r = tid >> 3, cq = tid & 7;
    int nb = n0 + cq * 4;
    const float* zr = p.z + (size_t)(b0 + r) * 64;
    const float* w1r = p.W1 + (size_t)nb * NPIN + 75;
    float a0 = p.b1[nb], a1 = p.b1[nb + 1], a2 = p.b1[nb + 2], a3 = p.b1[nb + 3];
    for (int k = 0; k < 64; ++k) {
      float zv = zr[k];
      a0 += zv * w1r[k]; a1 += zv * w1r[NPIN + k];
      a2 += zv * w1r[2 * NPIN + k]; a3 += zv * w1r[3 * NPIN + k];
    }
    f32x4 st = {a0, a1, a2, a3};
    *(f32x4*)(p.zc + (size_t)(b0 + r) * NH + nb) = st;
  }
  // Wa1 -> bf16 ws: rows n0+g*4..+3 over all (g,w) cover 1024 rows once
  for (int idx = tid; idx < 4 * NH; idx += 256) {
    int r = idx >> 10, k = idx & (NH - 1);
    int row = n0 + g * 4 + r;
    p.wa1b[(size_t)row * NH + k] = f2bf(p.Wa1[(size_t)row * NH + k]);
  }
  if (bid == 0) {  // Wa2 padded to 16 rows
    for (int idx = tid; idx < 16 * NH; idx += 256) {
      int r = idx >> 10, k = idx & (NH - 1);
      p.wa2b[idx] = (r < NJ) ? f2bf(p.Wa2[(size_t)r * NH + k]) : (unsigned short)0;
    }
  }
  if (bid == 1) {  // [Wo(3); Wv(42); zeros(3)] padded to 48 rows
    for (int idx = tid; idx < 48 * NH; idx += 256) {
      int r = idx >> 10, k = idx & (NH - 1);
      unsigned short v = 0;
      if (r < 3) v = f2bf(p.Wo[(size_t)r * NH + k]);
      else if (r < 45) v = f2bf(p.Wv[(size_t)(r - 3) * NH + k]);
      p.wexb[idx] = v;
    }
  }
  gbar(p.gcnt, 256u);  // one-time cross-XCD barrier (weight conversions)

  // ---------------- phase lambdas ----------------
  auto ln_row = [&](const float* y, const float* gamma, const float* beta,
                    unsigned short* hout) {
    f32x4 v = *(const f32x4*)(y + tid * 4);
    float s = v[0] + v[1] + v[2] + v[3];
    float q = v[0] * v[0] + v[1] * v[1] + v[2] * v[2] + v[3] * v[3];
#pragma unroll
    for (int off = 32; off; off >>= 1) {
      s += __shfl_down(s, off, 64);
      q += __shfl_down(q, off, 64);
    }
    if (lane == 0) { redm[wave] = s; redq[wave] = q; }
    __syncthreads();
    float m = (redm[0] + redm[1] + redm[2] + redm[3]) * (1.0f / 1024.0f);
    float e2 = (redq[0] + redq[1] + redq[2] + redq[3]) * (1.0f / 1024.0f);
    float rs = rsqrtf(e2 - m * m + 1e-5f);
    u16x4 hv;
#pragma unroll
    for (int i = 0; i < 4; ++i) {
      int c = tid * 4 + i;
      float x = (v[i] - m) * rs * gamma[c] + beta[c];
      hv[i] = f2bf(fmaxf(x, 0.f));
    }
    *(u16x4*)(hout + tid * 4) = hv;
  };

  auto P1 = [&](int t) {
    int r = tid >> 3, cq = tid & 7;
    int nb = n0 + cq * 4;
    float xj[24];
#pragma unroll
    for (int j = 0; j < NJ; ++j) {
      xj[j] = (pj_l[r * NJ + j] - jm_l[j]) * jri_l[j];
      xj[12 + j] = pdq_l[r * NJ + j];
    }
    f32x4 acc = *(const f32x4*)(p.zc + (size_t)(b0 + r) * NH + nb);
    const float* w1r = p.W1 + (size_t)nb * NPIN;
#pragma unroll
    for (int k = 0; k < 24; ++k) {
      float xv = xj[k];
      acc[0] += xv * w1r[k]; acc[1] += xv * w1r[NPIN + k];
      acc[2] += xv * w1r[2 * NPIN + k]; acc[3] += xv * w1r[3 * NPIN + k];
    }
    const float* ob = p.obs + ((size_t)(b0 + r) * NS + t) * 51;
    for (int o = 0; o < 51; ++o) {
      float ov = ob[o];
      acc[0] += ov * w1r[24 + o]; acc[1] += ov * w1r[NPIN + 24 + o];
      acc[2] += ov * w1r[2 * NPIN + 24 + o]; acc[3] += ov * w1r[3 * NPIN + 24 + o];
    }
    *(f32x4*)(y1g + (size_t)r * NH + nb) = acc;
  };

  auto P2 = [&]() {
    int rt = wave >> 1, ct = wave & 1;
    int kq = (lane >> 4) * 8;
    const unsigned short* a = h1g + (size_t)(rt * 16 + (lane & 15)) * NH + kq;
    const unsigned short* b = &w2l[(ct * 16 + (lane & 15)) * W2S + kq];
    f32x4 acc = dot1024(a, b);
    int col = n0 + ct * 16 + (lane & 15);
    float b2v = p.b2[col];
#pragma unroll
    for (int i = 0; i < 4; ++i) {
      int row = rt * 16 + (lane >> 4) * 4 + i;
      y2g[(size_t)row * NH + col] = acc[i] + b2v;
    }
  };

  auto P3 = [&](int t) {
    int rt = wave >> 1, ct = wave & 1;
    int kq = (lane >> 4) * 8;
    {
      const unsigned short* a = hg + (size_t)(rt * 16 + (lane & 15)) * NH + kq;
      const unsigned short* b = p.wa1b + (size_t)(n0 + ct * 16 + (lane & 15)) * NH + kq;
      f32x4 acc = dot1024(a, b);
      int col = n0 + ct * 16 + (lane & 15);
      float bav = p.ba1[col];
#pragma unroll
      for (int i = 0; i < 4; ++i) {
        int row = rt * 16 + (lane >> 4) * 4 + i;
        t1g[(size_t)row * NH + col] = f2bf(fmaxf(acc[i] + bav, 0.f));
      }
    }
    if (w >= 26 && wave == 3) {  // heads: [Wo|Wv] 6 extra 16x16 tiles
      int e = w - 26, cte = e >> 1, rte = e & 1;
      const unsigned short* a = hg + (size_t)(rte * 16 + (lane & 15)) * NH + kq;
      const unsigned short* b = p.wexb + (size_t)(cte * 16 + (lane & 15)) * NH + kq;
      f32x4 acc = dot1024(a, b);
      int ec = cte * 16 + (lane & 15);
#pragma unroll
      for (int i = 0; i < 4; ++i) {
        int row = rte * 16 + (lane >> 4) * 4 + i;
        int bb = b0 + row;
        if (ec < 3) {
          float val = acc[i] + bo_l[ec];
          p.out_gmu[((size_t)bb * NS + t) * NPD + 39 + ec] = (val - pm_l[39 + ec]) * psi_l[39 + ec];
        } else if (ec < 45) {
          int sv = ec - 3;
          float val = acc[i] + bv_l[sv];
          float sig = 0.05f + 0.45f / (1.f + expf(-val));
          p.out_ls[((size_t)bb * NS + t) * NPD + sv] = logf(sig);
        }
      }
    }
  };

  auto P4 = [&](int tp) {
    if (wave < 2) {
      int rt = wave;
      int kq = (lane >> 4) * 8;
      const unsigned short* a = t1g + (size_t)(rt * 16 + (lane & 15)) * NH + kq;
      const unsigned short* b = p.wa2b + (size_t)(lane & 15) * NH + kq;
      f32x4 acc = dot1024(a, b);
      int j = lane & 15;
      if (j < NJ) {
#pragma unroll
        for (int i = 0; i < 4; ++i) {
          int row = rt * 16 + (lane >> 4) * 4 + i;
          aex[row * 16 + j] = tanhf(acc[i] + ba2_l[j]);
        }
      }
    }
    __syncthreads();
    for (int idx = tid; idx < BROW * NJ; idx += 256) {
      int r = idx / NJ, j = idx - r * NJ;
      float av = aex[r * 16 + j];
      float pj = pj_l[idx];
      float tgt = av * 0.25f + ddp_l[j];
      float cj = pj + alpha_l[j] * (tgt - pj);
      cj = fminf(fmaxf(cj, lo_l[j]), hi_l[j]);
      pdq_l[idx] = (cj - pj) * 30.f;
      pj_l[idx] = cj;
      if (w == 0) {
        size_t o = ((size_t)(b0 + r) * NS + tp) * NJ + j;
        p.out_joint[o] = cj;
        p.out_act[o] = av;
      }
    }
    __syncthreads();
    if (w == 0) {
      for (int idx = tid; idx < BROW * 39; idx += 256) {
        int r = idx / 39, m = idx - r * 39;
        float s = p.fkb[m];
        const float* fw = p.fkW + m * NJ;
#pragma unroll
        for (int j = 0; j < NJ; ++j) s += pj_l[r * NJ + j] * fw[j];
        p.out_gmu[((size_t)(b0 + r) * NS + tp) * NPD + m] = (s - pm_l[m]) * psi_l[m];
      }
    }
    __syncthreads();
  };

  // ---------------- step loop: 5 XCD-local barriers / step ----------------
  unsigned int nbar = 0;
  for (int t = 0; t < NS; ++t) {
    if (t > 0) P4(t - 1);
    P1(t);
    xbar(cg, (++nbar) * WPG);       // y1 complete
    ln_row(y1g + (size_t)w * NH, p.g1, p.be1, h1g + (size_t)w * NH);
    xbar(cg, (++nbar) * WPG);       // h1 complete
    P2();
    xbar(cg, (++nbar) * WPG);       // y2 complete
    ln_row(y2g + (size_t)w * NH, p.g2, p.be2, hg + (size_t)w * NH);
    xbar(cg, (++nbar) * WPG);       // h complete
    P3(t);
    xbar(cg, (++nbar) * WPG);       // t1 + heads complete
  }
  P4(NS - 1);
}

extern "C" void kernel_launch(void* const* d_in, const int* in_sizes, int n_in,
                              void* d_out, int out_size, void* d_ws, size_t ws_size,
                              hipStream_t stream) {
  (void)in_sizes; (void)n_in; (void)out_size; (void)ws_size;
  char* ws = (char*)d_ws;
  Params p;
  p.z = (const float*)d_in[0];   p.obs = (const float*)d_in[1];
  p.W1 = (const float*)d_in[2];  p.b1 = (const float*)d_in[3];
  p.g1 = (const float*)d_in[4];  p.be1 = (const float*)d_in[5];
  p.W2 = (const float*)d_in[6];  p.b2 = (const float*)d_in[7];
  p.g2 = (const float*)d_in[8];  p.be2 = (const float*)d_in[9];
  p.Wa1 = (const float*)d_in[10]; p.ba1 = (const float*)d_in[11];
  p.Wa2 = (const float*)d_in[12]; p.ba2 = (const float*)d_in[13];
  p.Wo = (const float*)d_in[14]; p.bo = (const float*)d_in[15];
  p.Wv = (const float*)d_in[16]; p.bv = (const float*)d_in[17];
  p.alog = (const float*)d_in[18];
  p.fkW = (const float*)d_in[19]; p.fkb = (const float*)d_in[20];
  p.pmean = (const float*)d_in[21]; p.pstd = (const float*)d_in[22];
  p.jlo = (const float*)d_in[23]; p.jhi = (const float*)d_in[24];
  p.ddp = (const float*)d_in[25];

  float* out = (float*)d_out;
  p.out_gmu = out;
  p.out_joint = out + (size_t)256 * 128 * 42;
  p.out_act = p.out_joint + (size_t)256 * 128 * 12;
  p.out_ls = p.out_act + (size_t)256 * 128 * 12;

  p.gcnt = (unsigned int*)(ws + 0);
  p.cnt = (unsigned int*)(ws + 256);
  p.zc = (float*)(ws + 4096);
  p.y1 = (float*)(ws + 4096 + (1 << 20));
  p.y2 = (float*)(ws + 4096 + 2 * (1 << 20));
  p.h1 = (unsigned short*)(ws + 4096 + 3 * (1 << 20));
  p.hh = (unsigned short*)(ws + 4096 + 3 * (1 << 20) + (1 << 19));
  p.t1 = (unsigned short*)(ws + 4096 + 3 * (1 << 20) + 2 * (1 << 19));
  p.wa1b = (unsigned short*)(ws + 4096 + 3 * (1 << 20) + 3 * (1 << 19));
  p.wa2b = (unsigned short*)(ws + 4096 + 5 * (1 << 20) + 3 * (1 << 19));
  p.wexb = (unsigned short*)(ws + 4096 + 5 * (1 << 20) + 3 * (1 << 19) + 32768);

  // counters must start at 0 each call (monotonic within a call)
  hipMemsetAsync(d_ws, 0, 4096, stream);
  decoder_persistent<<<dim3(256), dim3(256), 0, stream>>>(p);
}

// Round 5
// 4873.454 us; speedup vs baseline: 6.5097x; 1.9468x over previous
//
#include <hip/hip_runtime.h>
#include <math.h>

// Decoder_82231443849250: persistent-kernel recurrent MLP decoder.
// 8 batch-groups (32 rows each) x 32 WGs (32-col N-slices); group g = bid&7
// so a group's WGs land on one XCD under the default %8 round-robin mapping.
// Intra-group barrier:
//   release: s_waitcnt vmcnt(0)  (L1 is write-through -> stores live in XCD L2)
//   arrival: one relaxed agent-scope fetch_add (executes at coherence point)
//   poll:    global_load sc0 sc1 (bypass L1+L2, read coherence point; fresh,
//            non-exclusive -> no RMW serialization among 32 waiters)
//   acquire: buffer_inv sc0 (invalidate this CU's vector L1 ONLY; the shared
//            XCD L2 is the coherence point for intra-group data, keep it hot)
// All spins carry an s_memrealtime bailout so bugs terminate instead of hang.

#define NB 256
#define NS 128
#define NH 1024
#define NJ 12
#define NPIN 139
#define NPD 42
#define WPG 32
#define BROW 32
#define W2S 1032  // LDS row stride in ushorts

typedef __attribute__((ext_vector_type(8))) short short8;
typedef __attribute__((ext_vector_type(4))) float f32x4;
typedef __attribute__((ext_vector_type(4))) unsigned short u16x4;

struct Params {
  const float* z; const float* obs; const float* W1; const float* b1;
  const float* g1; const float* be1; const float* W2; const float* b2;
  const float* g2; const float* be2; const float* Wa1; const float* ba1;
  const float* Wa2; const float* ba2; const float* Wo; const float* bo;
  const float* Wv; const float* bv; const float* alog; const float* fkW;
  const float* fkb; const float* pmean; const float* pstd; const float* jlo;
  const float* jhi; const float* ddp;
  float* out_gmu; float* out_joint; float* out_act; float* out_ls;
  float* zc; float* y1; float* y2;
  unsigned short* h1; unsigned short* hh; unsigned short* t1;
  unsigned short* wa1b; unsigned short* wa2b; unsigned short* wexb;
  unsigned int* gcnt; unsigned int* cnt;
};

__device__ __forceinline__ unsigned short f2bf(float x) {
  union { float f; unsigned u; } v; v.f = x;
  unsigned r = v.u + 0x7FFFu + ((v.u >> 16) & 1u);
  return (unsigned short)(r >> 16);
}

__device__ __forceinline__ f32x4 dot1024(const unsigned short* a, const unsigned short* b) {
  const short8* ap = (const short8*)a;
  const short8* bp = (const short8*)b;
  f32x4 acc0 = {0.f, 0.f, 0.f, 0.f};
  f32x4 acc1 = {0.f, 0.f, 0.f, 0.f};
#pragma unroll 4
  for (int k8 = 0; k8 < 128; k8 += 8) {
    acc0 = __builtin_amdgcn_mfma_f32_16x16x32_bf16(ap[k8], bp[k8], acc0, 0, 0, 0);
    acc1 = __builtin_amdgcn_mfma_f32_16x16x32_bf16(ap[k8 + 4], bp[k8 + 4], acc1, 0, 0, 0);
  }
  return acc0 + acc1;
}

// ---- one-time global barrier (cross-XCD safe): full fences, used once.
__device__ __forceinline__ void gbar(unsigned int* c, unsigned int target) {
  __threadfence();
  __syncthreads();
  if (threadIdx.x == 0) {
    __hip_atomic_fetch_add(c, 1u, __ATOMIC_RELEASE, __HIP_MEMORY_SCOPE_AGENT);
    unsigned long long t0 = __builtin_amdgcn_s_memrealtime();
    while (__hip_atomic_load(c, __ATOMIC_ACQUIRE, __HIP_MEMORY_SCOPE_AGENT) < target) {
      __builtin_amdgcn_s_sleep(16);
      if (__builtin_amdgcn_s_memrealtime() - t0 > (1ull << 25)) break;  // bail, never hang
    }
  }
  __syncthreads();
  __threadfence();
}

// ---- XCD-local barrier (see header comment).
__device__ __forceinline__ void xbar(unsigned int* c, unsigned int target) {
  asm volatile("s_waitcnt vmcnt(0)" ::: "memory");
  __syncthreads();
  if (threadIdx.x == 0) {
    __hip_atomic_fetch_add(c, 1u, __ATOMIC_RELAXED, __HIP_MEMORY_SCOPE_AGENT);
    unsigned long long t0 = __builtin_amdgcn_s_memrealtime();
    for (;;) {
      unsigned v;
      asm volatile("global_load_dword %0, %1, off sc0 sc1\n\t"
                   "s_waitcnt vmcnt(0)"
                   : "=v"(v) : "v"(c) : "memory");
      if (v >= target) break;
      __builtin_amdgcn_s_sleep(2);
      if (__builtin_amdgcn_s_memrealtime() - t0 > (1ull << 23)) break;  // bail, never hang
    }
  }
  __syncthreads();
  asm volatile("buffer_inv sc0" ::: "memory");  // invalidate vector L1 only
}

__global__ __launch_bounds__(256, 2) void decoder_persistent(Params p) {
  __shared__ unsigned short w2l[BROW * W2S];
  __shared__ float pj_l[BROW * NJ];
  __shared__ float pdq_l[BROW * NJ];
  __shared__ float aex[BROW * 16];
  __shared__ float redm[4], redq[4];
  __shared__ float alpha_l[NJ], jm_l[NJ], jri_l[NJ], lo_l[NJ], hi_l[NJ], ddp_l[NJ], ba2_l[NJ];
  __shared__ float pm_l[NPD], psi_l[NPD], bv_l[NPD], bo_l[4];

  const int tid = threadIdx.x;
  const int bid = blockIdx.x;
  const int g = bid & 7;        // group == XCD under default %8 round-robin
  const int w = bid >> 3;       // WG-in-group: owns cols [w*32, w*32+32)
  const int b0 = g * BROW;
  const int n0 = w * 32;
  const int wave = tid >> 6;
  const int lane = tid & 63;

  unsigned int* cg = p.cnt + g * 64;  // own 256B line per group

  float* y1g = p.y1 + (size_t)g * BROW * NH;
  float* y2g = p.y2 + (size_t)g * BROW * NH;
  unsigned short* h1g = p.h1 + (size_t)g * BROW * NH;
  unsigned short* hg = p.hh + (size_t)g * BROW * NH;
  unsigned short* t1g = p.t1 + (size_t)g * BROW * NH;

  // ---------------- P0: one-time setup ----------------
  if (tid < NJ) {
    alpha_l[tid] = 1.f / (1.f + expf(-p.alog[tid]));
    float lo = p.jlo[tid], hi = p.jhi[tid];
    jm_l[tid] = 0.5f * (hi + lo);
    jri_l[tid] = 2.f / (hi - lo);
    lo_l[tid] = lo; hi_l[tid] = hi;
    ddp_l[tid] = p.ddp[tid]; ba2_l[tid] = p.ba2[tid];
  }
  if (tid < NPD) { pm_l[tid] = p.pmean[tid]; psi_l[tid] = 1.f / p.pstd[tid]; bv_l[tid] = p.bv[tid]; }
  if (tid < 3) bo_l[tid] = p.bo[tid];
  for (int idx = tid; idx < BROW * NJ; idx += 256) { pj_l[idx] = p.ddp[idx % NJ]; pdq_l[idx] = 0.f; }
  for (int idx = tid; idx < BROW * NH; idx += 256) {
    int r = idx >> 10, k = idx & (NH - 1);
    w2l[r * W2S + k] = f2bf(p.W2[(size_t)(n0 + r) * NH + k]);
  }
  {  // zc = z @ W1z^T + b1 (constant across steps)
    int r = tid >> 3, cq = tid & 7;
    int nb = n0 + cq * 4;
    const float* zr = p.z + (size_t)(b0 + r) * 64;
    const float* w1r = p.W1 + (size_t)nb * NPIN + 75;
    float a0 = p.b1[nb], a1 = p.b1[nb + 1], a2 = p.b1[nb + 2], a3 = p.b1[nb + 3];
    for (int k = 0; k < 64; ++k) {
      float zv = zr[k];
      a0 += zv * w1r[k]; a1 += zv * w1r[NPIN + k];
      a2 += zv * w1r[2 * NPIN + k]; a3 += zv * w1r[3 * NPIN + k];
    }
    f32x4 st = {a0, a1, a2, a3};
    *(f32x4*)(p.zc + (size_t)(b0 + r) * NH + nb) = st;
  }
  // Wa1 -> bf16 ws: rows n0+g*4..+3 over all (g,w) cover 1024 rows once
  for (int idx = tid; idx < 4 * NH; idx += 256) {
    int r = idx >> 10, k = idx & (NH - 1);
    int row = n0 + g * 4 + r;
    p.wa1b[(size_t)row * NH + k] = f2bf(p.Wa1[(size_t)row * NH + k]);
  }
  if (bid == 0) {  // Wa2 padded to 16 rows
    for (int idx = tid; idx < 16 * NH; idx += 256) {
      int r = idx >> 10, k = idx & (NH - 1);
      p.wa2b[idx] = (r < NJ) ? f2bf(p.Wa2[(size_t)r * NH + k]) : (unsigned short)0;
    }
  }
  if (bid == 1) {  // [Wo(3); Wv(42); zeros(3)] padded to 48 rows
    for (int idx = tid; idx < 48 * NH; idx += 256) {
      int r = idx >> 10, k = idx & (NH - 1);
      unsigned short v = 0;
      if (r < 3) v = f2bf(p.Wo[(size_t)r * NH + k]);
      else if (r < 45) v = f2bf(p.Wv[(size_t)(r - 3) * NH + k]);
      p.wexb[idx] = v;
    }
  }
  gbar(p.gcnt, 256u);  // one-time cross-XCD barrier (weight conversions)

  // ---------------- phase lambdas ----------------
  auto ln_row = [&](const float* y, const float* gamma, const float* beta,
                    unsigned short* hout) {
    f32x4 v = *(const f32x4*)(y + tid * 4);
    float s = v[0] + v[1] + v[2] + v[3];
    float q = v[0] * v[0] + v[1] * v[1] + v[2] * v[2] + v[3] * v[3];
#pragma unroll
    for (int off = 32; off; off >>= 1) {
      s += __shfl_down(s, off, 64);
      q += __shfl_down(q, off, 64);
    }
    if (lane == 0) { redm[wave] = s; redq[wave] = q; }
    __syncthreads();
    float m = (redm[0] + redm[1] + redm[2] + redm[3]) * (1.0f / 1024.0f);
    float e2 = (redq[0] + redq[1] + redq[2] + redq[3]) * (1.0f / 1024.0f);
    float rs = rsqrtf(e2 - m * m + 1e-5f);
    u16x4 hv;
#pragma unroll
    for (int i = 0; i < 4; ++i) {
      int c = tid * 4 + i;
      float x = (v[i] - m) * rs * gamma[c] + beta[c];
      hv[i] = f2bf(fmaxf(x, 0.f));
    }
    *(u16x4*)(hout + tid * 4) = hv;
  };

  auto P1 = [&](int t) {
    int r = tid >> 3, cq = tid & 7;
    int nb = n0 + cq * 4;
    float xj[24];
#pragma unroll
    for (int j = 0; j < NJ; ++j) {
      xj[j] = (pj_l[r * NJ + j] - jm_l[j]) * jri_l[j];
      xj[12 + j] = pdq_l[r * NJ + j];
    }
    f32x4 acc = *(const f32x4*)(p.zc + (size_t)(b0 + r) * NH + nb);
    const float* w1r = p.W1 + (size_t)nb * NPIN;
#pragma unroll
    for (int k = 0; k < 24; ++k) {
      float xv = xj[k];
      acc[0] += xv * w1r[k]; acc[1] += xv * w1r[NPIN + k];
      acc[2] += xv * w1r[2 * NPIN + k]; acc[3] += xv * w1r[3 * NPIN + k];
    }
    const float* ob = p.obs + ((size_t)(b0 + r) * NS + t) * 51;
    for (int o = 0; o < 51; ++o) {
      float ov = ob[o];
      acc[0] += ov * w1r[24 + o]; acc[1] += ov * w1r[NPIN + 24 + o];
      acc[2] += ov * w1r[2 * NPIN + 24 + o]; acc[3] += ov * w1r[3 * NPIN + 24 + o];
    }
    *(f32x4*)(y1g + (size_t)r * NH + nb) = acc;
  };

  auto P2 = [&]() {
    int rt = wave >> 1, ct = wave & 1;
    int kq = (lane >> 4) * 8;
    const unsigned short* a = h1g + (size_t)(rt * 16 + (lane & 15)) * NH + kq;
    const unsigned short* b = &w2l[(ct * 16 + (lane & 15)) * W2S + kq];
    f32x4 acc = dot1024(a, b);
    int col = n0 + ct * 16 + (lane & 15);
    float b2v = p.b2[col];
#pragma unroll
    for (int i = 0; i < 4; ++i) {
      int row = rt * 16 + (lane >> 4) * 4 + i;
      y2g[(size_t)row * NH + col] = acc[i] + b2v;
    }
  };

  auto P3 = [&](int t) {
    int rt = wave >> 1, ct = wave & 1;
    int kq = (lane >> 4) * 8;
    {
      const unsigned short* a = hg + (size_t)(rt * 16 + (lane & 15)) * NH + kq;
      const unsigned short* b = p.wa1b + (size_t)(n0 + ct * 16 + (lane & 15)) * NH + kq;
      f32x4 acc = dot1024(a, b);
      int col = n0 + ct * 16 + (lane & 15);
      float bav = p.ba1[col];
#pragma unroll
      for (int i = 0; i < 4; ++i) {
        int row = rt * 16 + (lane >> 4) * 4 + i;
        t1g[(size_t)row * NH + col] = f2bf(fmaxf(acc[i] + bav, 0.f));
      }
    }
    if (w >= 26 && wave == 3) {  // heads: [Wo|Wv] 6 extra 16x16 tiles
      int e = w - 26, cte = e >> 1, rte = e & 1;
      const unsigned short* a = hg + (size_t)(rte * 16 + (lane & 15)) * NH + kq;
      const unsigned short* b = p.wexb + (size_t)(cte * 16 + (lane & 15)) * NH + kq;
      f32x4 acc = dot1024(a, b);
      int ec = cte * 16 + (lane & 15);
#pragma unroll
      for (int i = 0; i < 4; ++i) {
        int row = rte * 16 + (lane >> 4) * 4 + i;
        int bb = b0 + row;
        if (ec < 3) {
          float val = acc[i] + bo_l[ec];
          p.out_gmu[((size_t)bb * NS + t) * NPD + 39 + ec] = (val - pm_l[39 + ec]) * psi_l[39 + ec];
        } else if (ec < 45) {
          int sv = ec - 3;
          float val = acc[i] + bv_l[sv];
          float sig = 0.05f + 0.45f / (1.f + expf(-val));
          p.out_ls[((size_t)bb * NS + t) * NPD + sv] = logf(sig);
        }
      }
    }
  };

  auto P4 = [&](int tp) {
    if (wave < 2) {
      int rt = wave;
      int kq = (lane >> 4) * 8;
      const unsigned short* a = t1g + (size_t)(rt * 16 + (lane & 15)) * NH + kq;
      const unsigned short* b = p.wa2b + (size_t)(lane & 15) * NH + kq;
      f32x4 acc = dot1024(a, b);
      int j = lane & 15;
      if (j < NJ) {
#pragma unroll
        for (int i = 0; i < 4; ++i) {
          int row = rt * 16 + (lane >> 4) * 4 + i;
          aex[row * 16 + j] = tanhf(acc[i] + ba2_l[j]);
        }
      }
    }
    __syncthreads();
    for (int idx = tid; idx < BROW * NJ; idx += 256) {
      int r = idx / NJ, j = idx - r * NJ;
      float av = aex[r * 16 + j];
      float pj = pj_l[idx];
      float tgt = av * 0.25f + ddp_l[j];
      float cj = pj + alpha_l[j] * (tgt - pj);
      cj = fminf(fmaxf(cj, lo_l[j]), hi_l[j]);
      pdq_l[idx] = (cj - pj) * 30.f;
      pj_l[idx] = cj;
      if (w == 0) {
        size_t o = ((size_t)(b0 + r) * NS + tp) * NJ + j;
        p.out_joint[o] = cj;
        p.out_act[o] = av;
      }
    }
    __syncthreads();
    if (w == 0) {
      for (int idx = tid; idx < BROW * 39; idx += 256) {
        int r = idx / 39, m = idx - r * 39;
        float s = p.fkb[m];
        const float* fw = p.fkW + m * NJ;
#pragma unroll
        for (int j = 0; j < NJ; ++j) s += pj_l[r * NJ + j] * fw[j];
        p.out_gmu[((size_t)(b0 + r) * NS + tp) * NPD + m] = (s - pm_l[m]) * psi_l[m];
      }
    }
    __syncthreads();
  };

  // ---------------- step loop: 5 XCD-local barriers / step ----------------
  unsigned int nbar = 0;
  for (int t = 0; t < NS; ++t) {
    if (t > 0) P4(t - 1);
    P1(t);
    xbar(cg, (++nbar) * WPG);       // y1 complete
    ln_row(y1g + (size_t)w * NH, p.g1, p.be1, h1g + (size_t)w * NH);
    xbar(cg, (++nbar) * WPG);       // h1 complete
    P2();
    xbar(cg, (++nbar) * WPG);       // y2 complete
    ln_row(y2g + (size_t)w * NH, p.g2, p.be2, hg + (size_t)w * NH);
    xbar(cg, (++nbar) * WPG);       // h complete
    P3(t);
    xbar(cg, (++nbar) * WPG);       // t1 + heads complete
  }
  P4(NS - 1);
}

extern "C" void kernel_launch(void* const* d_in, const int* in_sizes, int n_in,
                              void* d_out, int out_size, void* d_ws, size_t ws_size,
                              hipStream_t stream) {
  (void)in_sizes; (void)n_in; (void)out_size; (void)ws_size;
  char* ws = (char*)d_ws;
  Params p;
  p.z = (const float*)d_in[0];   p.obs = (const float*)d_in[1];
  p.W1 = (const float*)d_in[2];  p.b1 = (const float*)d_in[3];
  p.g1 = (const float*)d_in[4];  p.be1 = (const float*)d_in[5];
  p.W2 = (const float*)d_in[6];  p.b2 = (const float*)d_in[7];
  p.g2 = (const float*)d_in[8];  p.be2 = (const float*)d_in[9];
  p.Wa1 = (const float*)d_in[10]; p.ba1 = (const float*)d_in[11];
  p.Wa2 = (const float*)d_in[12]; p.ba2 = (const float*)d_in[13];
  p.Wo = (const float*)d_in[14]; p.bo = (const float*)d_in[15];
  p.Wv = (const float*)d_in[16]; p.bv = (const float*)d_in[17];
  p.alog = (const float*)d_in[18];
  p.fkW = (const float*)d_in[19]; p.fkb = (const float*)d_in[20];
  p.pmean = (const float*)d_in[21]; p.pstd = (const float*)d_in[22];
  p.jlo = (const float*)d_in[23]; p.jhi = (const float*)d_in[24];
  p.ddp = (const float*)d_in[25];

  float* out = (float*)d_out;
  p.out_gmu = out;
  p.out_joint = out + (size_t)256 * 128 * 42;
  p.out_act = p.out_joint + (size_t)256 * 128 * 12;
  p.out_ls = p.out_act + (size_t)256 * 128 * 12;

  p.gcnt = (unsigned int*)(ws + 0);
  p.cnt = (unsigned int*)(ws + 256);
  p.zc = (float*)(ws + 4096);
  p.y1 = (float*)(ws + 4096 + (1 << 20));
  p.y2 = (float*)(ws + 4096 + 2 * (1 << 20));
  p.h1 = (unsigned short*)(ws + 4096 + 3 * (1 << 20));
  p.hh = (unsigned short*)(ws + 4096 + 3 * (1 << 20) + (1 << 19));
  p.t1 = (unsigned short*)(ws + 4096 + 3 * (1 << 20) + 2 * (1 << 19));
  p.wa1b = (unsigned short*)(ws + 4096 + 3 * (1 << 20) + 3 * (1 << 19));
  p.wa2b = (unsigned short*)(ws + 4096 + 5 * (1 << 20) + 3 * (1 << 19));
  p.wexb = (unsigned short*)(ws + 4096 + 5 * (1 << 20) + 3 * (1 << 19) + 32768);

  // counters must start at 0 each call (monotonic within a call)
  hipMemsetAsync(d_ws, 0, 4096, stream);
  decoder_persistent<<<dim3(256), dim3(256), 0, stream>>>(p);
}